// Round 8
// baseline (132.029 us; speedup 1.0000x reference)
//
#include <hip/hip_runtime.h>
#include <stdint.h>

// Problem constants (reference: B=2, C=4, SPATIAL=(128,128,128), N_PTS=32, THR=0.5)
#define Bn 2
#define Cn 4
#define Sn (128 * 128 * 128)   // 2^21 voxels per (b,c)
#define NPTS 32
#define NBINS 1025             // probs in (0.5, 1] -> one binade; (bits-0x3F000000)>>13 in [0,1024]
#define THRf 0.5f
#define PB 4096                // voxels per block in the streaming pass
#define BT 512                 // streaming threads/block: 8 waves
#define BT2 1024               // select threads/block
#define FB 1024                // per-class survivor cap in select (expected m ~ 80)
#define QCAP 3072              // per-block screen-survivor queue cap (expected max ~1500)

typedef float f32x4 __attribute__((ext_vector_type(4)));

__device__ __forceinline__ int bin_of_bits(unsigned int u) {
    return (int)((u - 0x3F000000u) >> 13);
}

// Softmax over the 4 classes at one voxel; mirrors jax.nn.softmax exactly
// (exp(x-max)/sum, sequential sum c=0..3). Only the argmax class can exceed 0.5.
// DO NOT re-associate or swap expf for __expf here: bit-exactness with the jax
// reference (ocml expf + precise IEEE divide) is load-bearing.
__device__ __forceinline__ void softmax_argmax4(float l0, float l1, float l2, float l3,
                                                int* cm_out, float* p_out) {
    float m = fmaxf(fmaxf(l0, l1), fmaxf(l2, l3));
    float e0 = expf(l0 - m);
    float e1 = expf(l1 - m);
    float e2 = expf(l2 - m);
    float e3 = expf(l3 - m);
    float s = ((e0 + e1) + e2) + e3;
    float em = e0; int cm = 0;
    if (e1 > em) { em = e1; cm = 1; }
    if (e2 > em) { em = e2; cm = 2; }
    if (e3 > em) { em = e3; cm = 3; }
    *cm_out = cm;
    *p_out = em / s;
}

// Lessons ledger (measured on MI355X):
// R9:  per-block __threadfence in a 1024-block kernel = buffer_wbl2 storm (345us).
// R10: 2-block epilogue with dependent L2-cold loads = 88us tail.
// R11: 4x-parallel epilogue + branch-free 8-deep loads -> tail ~5us.
// R12: iflag spin-gate regressed ~30us; hoist w/o fence got re-sunk. Reverted.
// R13: two-dispatch beats in-dispatch coherence: 117.8us total (session best).
//      fused_stream ~40us = 4x BW floor with 12.4us VALU -> latency-starved.
// R14: sched_barrier(0) hoist = neutral (120.0). Source-level ILP shaping is
//      0-for-3. The chain itself must shrink.
// R15 (this round): key identity: m = max(l) => e_argmax = expf(0) = 1.0 exactly
//      => p > 0.5  <=>  s < 2.0. A native-exp screen (v_exp_f32, err ~2^-20)
//      certifies non-survivors via s~ >= 2.001 (conservative margin >> error).
//      Per-lane branching wouldn't save issue slots (P(all 64 lanes skip)~0), so
//      survivors are ballot-compacted into an LDS queue and the precise ocml
//      path (UNCHANGED softmax_argmax4) runs densely on ~30% of voxels with
//      converged lanes (4-scalar L2-hot re-gather per survivor).

// ---------------- Kernel 1: streaming pass ----------------
__global__ __launch_bounds__(BT) void fused_stream(const float* __restrict__ logits,
                                                   unsigned int* __restrict__ cnt,
                                                   unsigned int* __restrict__ gh,
                                                   uint2* __restrict__ cand,
                                                   int cap) {
    __shared__ unsigned int lh[Cn * NBINS];   // 16.4 KB per-class local radix hist
    __shared__ unsigned short qidx[QCAP];     // 6 KB   screen-survivor local voxel ids
    __shared__ unsigned int qpv[QCAP];        // 12 KB  packed precise results (0=reject)
    __shared__ unsigned int lcut[Cn], cls_cnt[Cn], cls_base[Cn], cls_pos[Cn];
    __shared__ unsigned int qn;
    const int b = blockIdx.y;
    const int t = threadIdx.x;
    const int lane = t & 63;
    for (int j = t; j < Cn * NBINS; j += BT) lh[j] = 0u;
    if (t < Cn) { lcut[t] = 0u; cls_cnt[t] = 0u; cls_pos[t] = 0u; }
    if (t == 0) qn = 0u;
    __syncthreads();

    const float* base = logits + (size_t)b * Cn * Sn;
    const f32x4* s0 = (const f32x4*)base;
    const f32x4* s1 = (const f32x4*)(base + Sn);
    const f32x4* s2 = (const f32x4*)(base + 2 * Sn);
    const f32x4* s3 = (const f32x4*)(base + 3 * Sn);
    const int qs = blockIdx.x * (PB / 4);

    // phase 1-fast: native-exp screen over all 4096 voxels. s~ >= 2.001 is a
    // CERTIFICATE of p <= 0.5 (margin 5e-4 >> 4x native-exp relative error).
    // Screen-passers are ballot-compacted into the queue (order within the block
    // is irrelevant: final ranking is by exact (p bits, voxel idx)).
    #pragma unroll
    for (int it = 0; it < PB / 4 / BT; ++it) {   // 2 iterations
        int q = qs + it * BT + t;
        f32x4 v0 = s0[q], v1 = s1[q], v2 = s2[q], v3 = s3[q];
        #pragma unroll
        for (int k = 0; k < 4; ++k) {
            float l0 = v0[k], l1 = v1[k], l2 = v2[k], l3 = v3[k];
            float m = fmaxf(fmaxf(l0, l1), fmaxf(l2, l3));
            float st = ((__expf(l0 - m) + __expf(l1 - m)) + __expf(l2 - m)) + __expf(l3 - m);
            bool c = st < 2.001f;
            unsigned long long mk = __ballot(c);
            unsigned int wb = 0u;
            unsigned int nset = (unsigned int)__popcll(mk);
            if (lane == 0 && nset) wb = atomicAdd(&qn, nset);
            wb = __shfl(wb, 0);
            unsigned int pos = wb + __builtin_amdgcn_mbcnt_hi(
                (unsigned int)(mk >> 32),
                __builtin_amdgcn_mbcnt_lo((unsigned int)mk, 0u));
            if (c && pos < QCAP)
                qidx[pos] = (unsigned short)((it * BT + t) * 4 + k);
        }
    }
    __syncthreads();

    // phase 1-slow: dense precise pass over the ~30% screen survivors. Lanes are
    // converged; each re-gathers its voxel's 4 logits (L2-hot) and runs the
    // UNCHANGED exact softmax. Histogram built here (identical counts to before).
    const int nq = min((int)qn, QCAP);
    for (int i = t; i < nq; i += BT) {
        int lv = qidx[i];
        int gv = (qs << 2) + lv;   // global voxel index in this batch
        float l0 = base[gv], l1 = base[Sn + gv], l2 = base[2 * Sn + gv], l3 = base[3 * Sn + gv];
        int cm; float p;
        softmax_argmax4(l0, l1, l2, l3, &cm, &p);
        unsigned int pv = 0u;
        if (p > THRf) {
            unsigned int off = __float_as_uint(p) - 0x3F000000u;  // 1..0x800000
            atomicAdd(&lh[cm * NBINS + (int)(off >> 13)], 1u);    // no-return ds_add
            pv = (off << 2) | (unsigned int)cm;                   // 26 bits, nonzero
        }
        qpv[i] = pv;
    }
    __syncthreads();

    // phase 2: wave w (w<4) computes local cutoff for class w (64 lanes x 17 bins).
    // Entries below the local cutoff have >=32 strictly-greater local entries ->
    // global rank >= 32 -> safe to drop. Union over blocks is a superset of top-32.
    // The break-time acc = count of entries in bins >= lcut = exact emit count.
    {
        const int wave = t >> 6;
        if (wave < Cn) {
            const unsigned int* h = &lh[wave * NBINS];
            const int lo = lane * 17;
            unsigned int cs = 0;
            #pragma unroll
            for (int k = 0; k < 17; ++k) {
                int bin = lo + k;
                if (bin < NBINS) cs += h[bin];
            }
            unsigned int S = cs;  // inclusive suffix sum over lanes [lane..63]
            #pragma unroll
            for (int off = 1; off < 64; off <<= 1) {
                unsigned int v = __shfl_down(S, off, 64);
                if (lane + off < 64) S += v;
            }
            unsigned int suf = S - cs;
            if (S >= NPTS && suf < NPTS) {   // exactly one lane (when total >= 32)
                unsigned int acc = suf;
                int hi = min(lo + 16, NBINS - 1);
                for (int bin = hi; bin >= lo; --bin) {
                    acc += h[bin];
                    if (acc >= NPTS) {
                        lcut[wave] = (unsigned int)bin;
                        cls_cnt[wave] = acc;
                        break;
                    }
                }
            }
            if (lane == 0 && S < NPTS) cls_cnt[wave] = S;  // total<32: lcut=0, emit all
        }
    }
    __syncthreads();

    // phase 2.5: publish surviving bins (bin >= lcut, nonzero) into the global
    // per-(b,c) histogram == exactly the histogram of all emitted candidates.
    // Plain atomicAdd (device-scope by default); ~35 per class per block.
    {
        const int wave = t >> 6;
        if (wave < Cn) {
            const unsigned int* h = &lh[wave * NBINS];
            unsigned int* g = gh + (size_t)(b * Cn + wave) * NBINS;
            for (int bin = (int)lcut[wave] + lane; bin < NBINS; bin += 64) {
                unsigned int v = h[bin];
                if (v) atomicAdd(&g[bin], v);
            }
        }
    }
    // reservation: one global atomic per (block, class)
    if (t < Cn && cls_cnt[t] > 0)
        cls_base[t] = atomicAdd(&cnt[b * Cn + t], cls_cnt[t]);
    __syncthreads();

    // phase 3: emit survivors from the queue (~130/block total).
    // Plain stores: the kernel boundary makes them visible to the select kernel.
    for (int i = t; i < nq; i += BT) {
        unsigned int pv = qpv[i];
        if (pv != 0u) {
            unsigned int cm = pv & 3u;
            if ((pv >> 15) >= lcut[cm]) {   // pv>>15 == p_off>>13 == bin
                unsigned int pos = cls_base[cm] + atomicAdd(&cls_pos[cm], 1u);
                if (pos < (unsigned int)cap) {
                    unsigned int idx = (unsigned int)((qs << 2) + qidx[i]);
                    cand[(size_t)(b * Cn + cm) * cap + pos] =
                        make_uint2(0x3F000000u + (pv >> 2), idx);
                }
            }
        }
    }
}

// ---------------- Kernel 2: per-(b,c) exact selection + emit ----------------
// One block per (b,c). gh is already the complete candidate histogram, so this
// kernel does: exact cutoff scan -> ONE branch-free MLP filter pass over cand ->
// O(m^2) exact rank (m ~ 80) -> cross-class compaction by the last finisher of
// each batch (R0-proven 8-block threadfence pattern).
__global__ __launch_bounds__(BT2) void select_emit(const unsigned int* __restrict__ cnt,
                                                   const unsigned int* __restrict__ gh,
                                                   const uint2* __restrict__ cand,
                                                   int cap,
                                                   unsigned int* __restrict__ done,
                                                   unsigned int* __restrict__ validn,
                                                   uint2* __restrict__ topk,
                                                   int* __restrict__ out) {
    __shared__ unsigned int lh[NBINS];        // 4.1 KB this class's global hist
    __shared__ uint2 fbuf[FB];                // 8.2 KB survivors
    __shared__ unsigned int s_T, s_m, s_old;
    __shared__ int pre[Cn + 1];
    const int bc = blockIdx.x, t = threadIdx.x;
    const int b = bc >> 2;
    const int lane = t & 63;

    for (int j = t; j < NBINS; j += BT2) lh[j] = gh[(size_t)bc * NBINS + j];
    if (t == 0) { s_T = 0u; s_m = 0u; }
    __syncthreads();
    const int n = min((int)cnt[bc], cap);

    // exact global cutoff: wave 0 scans the 1025 bins
    if (t < 64) {
        const int lo = lane * 17;
        unsigned int cs = 0;
        #pragma unroll
        for (int k = 0; k < 17; ++k) {
            int bin = lo + k;
            if (bin < NBINS) cs += lh[bin];
        }
        unsigned int S = cs;
        #pragma unroll
        for (int off = 1; off < 64; off <<= 1) {
            unsigned int v = __shfl_down(S, off, 64);
            if (lane + off < 64) S += v;
        }
        unsigned int suf = S - cs;
        if (S >= NPTS && suf < NPTS) {
            unsigned int acc = suf;
            int hi = min(lo + 16, NBINS - 1);
            for (int bin = hi; bin >= lo; --bin) {
                acc += lh[bin];
                if (acc >= NPTS) { s_T = (unsigned int)bin; break; }
            }
        }
        // S < NPTS: s_T stays 0 -> keep everything
    }
    __syncthreads();
    const unsigned int T = s_T;

    // single filtered pass, branch-free 8-deep load batches (true MLP)
    {
        const uint2* src = cand + (size_t)bc * cap;
        for (int j0 = t; j0 < n; j0 += BT2 * 8) {
            uint2 e[8];
            #pragma unroll
            for (int k = 0; k < 8; ++k) {
                int j = j0 + k * BT2;
                e[k] = src[j < n ? j : (n > 0 ? n - 1 : 0)];   // clamped: always issues
            }
            #pragma unroll
            for (int k = 0; k < 8; ++k) {
                int j = j0 + k * BT2;
                if (j < n && (unsigned int)bin_of_bits(e[k].x) >= T) {
                    unsigned int pos = atomicAdd(&s_m, 1u);
                    if (pos < FB) fbuf[pos] = e[k];
                }
            }
        }
    }
    __syncthreads();

    // exact rank with jax tie-break (higher prob first; equal prob -> lower idx
    // first); ranks distinct (idx unique per class). ~80 survivors.
    const int m = min((int)s_m, FB);
    const int vn = min(n, NPTS);
    if (t == 0) validn[bc] = (unsigned int)vn;
    for (int i = t; i < m; i += BT2) {
        uint2 e = fbuf[i];
        int rank = 0;
        for (int j = 0; j < m; ++j) {
            uint2 o = fbuf[j];
            rank += (int)((o.x > e.x) || (o.x == e.x && o.y < e.y));
        }
        if (rank < vn) topk[bc * NPTS + rank] = e;
    }

    // epilogue: last finishing block of this batch emits (8 blocks total pay the
    // fence -- the R0-proven pattern).
    __threadfence();
    __syncthreads();
    if (t == 0) s_old = atomicAdd(&done[b], 1u);
    __syncthreads();
    if (s_old != 3u) return;
    __threadfence();   // acquire: see the other 3 classes' topk/validn

    if (t == 0) {
        int acc = 0;
        for (int oc = 0; oc < Cn; ++oc) {
            pre[oc] = acc;
            acc += (int)validn[b * Cn + ((oc + 1) & 3)];   // class order [1,2,3,0]
        }
        pre[Cn] = acc;
    }
    __syncthreads();

    if (t < Cn * NPTS) {   // 128 output slots for batch b
        const int j = t;
        int label = -1, z = 0, y = 0, x = 0;
        if (j < pre[Cn]) {
            int oc = 0;
            while (j >= pre[oc + 1]) ++oc;
            int c = (oc + 1) & 3;
            int r = j - pre[oc];
            uint2 e = topk[(b * Cn + c) * NPTS + r];
            int idx = (int)e.y;
            z = idx >> 14;          // idx / (128*128)
            y = (idx >> 7) & 127;   // (idx / 128) % 128
            x = idx & 127;          // idx % 128
            label = c;
        }
        int* coords = out;                       // 2*128*3 = 768 ints
        int* labels = out + Bn * Cn * NPTS * 3;  // then 2*128 = 256 ints
        int bo = b * Cn * NPTS + j;
        coords[bo * 3 + 0] = z;
        coords[bo * 3 + 1] = y;
        coords[bo * 3 + 2] = x;
        labels[bo] = label;
    }
}

extern "C" void kernel_launch(void* const* d_in, const int* in_sizes, int n_in,
                              void* d_out, int out_size, void* d_ws, size_t ws_size,
                              hipStream_t stream) {
    const float* logits = (const float*)d_in[0];
    int* out = (int*)d_out;

    // Workspace layout (zeroed region first, contiguous: cnt, done, gh)
    unsigned int* cnt = (unsigned int*)d_ws;             // 8 u32    @0
    unsigned int* done = cnt + Bn * Cn;                  // 2 u32    @32
    unsigned int* gh = done + Bn;                        // 8*1025   @40
    unsigned int* validn = gh + Bn * Cn * NBINS;         // 8 u32    @32840
    uint2* topk = (uint2*)(validn + Bn * Cn);            // 256 uint2 @32872 (8-aligned)
    uint2* cand = topk + Bn * Cn * NPTS;                 // @34920
    size_t fixed = (size_t)((char*)cand - (char*)d_ws);
    int cap = (int)((ws_size - fixed) / (Bn * Cn * sizeof(uint2)));
    if (cap > (1 << 18)) cap = 1 << 18;   // 256k entries/bc >> the ~18k expected
    if (cap < 4096) cap = 4096;

    // Zero cnt + done + gh (contiguous, ~33 KB; workspace is harness-poisoned)
    hipMemsetAsync(cnt, 0, (size_t)(Bn * Cn + Bn + Bn * Cn * NBINS) * sizeof(unsigned int),
                   stream);

    dim3 grid(Sn / PB, Bn);   // (512, 2) = 1024 blocks, co-resident at 4 blk/CU
    fused_stream<<<grid, BT, 0, stream>>>(logits, cnt, gh, cand, cap);
    select_emit<<<Bn * Cn, BT2, 0, stream>>>(cnt, gh, cand, cap, done, validn, topk, out);
}

// Round 9
// 119.569 us; speedup vs baseline: 1.1042x; 1.1042x over previous
//
#include <hip/hip_runtime.h>
#include <stdint.h>

// Problem constants (reference: B=2, C=4, SPATIAL=(128,128,128), N_PTS=32, THR=0.5)
#define Bn 2
#define Cn 4
#define Sn (128 * 128 * 128)   // 2^21 voxels per (b,c)
#define NPTS 32
#define NBINS 1025             // probs in (0.5, 1] -> one binade; (bits-0x3F000000)>>13 in [0,1024]
#define THRf 0.5f
#define PB 4096                // voxels per block in the streaming pass
#define BT 512                 // streaming threads/block: 8 waves
#define BT2 1024               // select threads/block
#define FB 1024                // per-class survivor cap in select (expected m ~ 80)
#define QW 128                 // per-wave screen-survivor queue (mean ~18, +26 sigma headroom)

typedef float f32x4 __attribute__((ext_vector_type(4)));

__device__ __forceinline__ int bin_of_bits(unsigned int u) {
    return (int)((u - 0x3F000000u) >> 13);
}

// Softmax over the 4 classes at one voxel; mirrors jax.nn.softmax exactly
// (exp(x-max)/sum, sequential sum c=0..3). Only the argmax class can exceed 0.5.
// DO NOT re-associate or swap expf for __expf here: bit-exactness with the jax
// reference (ocml expf + precise IEEE divide) is load-bearing.
__device__ __forceinline__ void softmax_argmax4(float l0, float l1, float l2, float l3,
                                                int* cm_out, float* p_out) {
    float m = fmaxf(fmaxf(l0, l1), fmaxf(l2, l3));
    float e0 = expf(l0 - m);
    float e1 = expf(l1 - m);
    float e2 = expf(l2 - m);
    float e3 = expf(l3 - m);
    float s = ((e0 + e1) + e2) + e3;
    float em = e0; int cm = 0;
    if (e1 > em) { em = e1; cm = 1; }
    if (e2 > em) { em = e2; cm = 2; }
    if (e3 > em) { em = e3; cm = 3; }
    *cm_out = cm;
    *p_out = em / s;
}

// Lessons ledger (measured on MI355X):
// R9:  per-block __threadfence in a 1024-block kernel = buffer_wbl2 storm (345us).
// R10: 2-block epilogue with dependent L2-cold loads = 88us tail.
// R11: 4x-parallel epilogue + branch-free 8-deep loads -> tail ~5us.
// R12: iflag spin-gate regressed ~30us; hoist w/o fence got re-sunk. Reverted.
// R13: two-dispatch beats in-dispatch coherence: 117.8us total (session best).
// R14: sched_barrier(0) hoist neutral. Source ILP shaping 0-for-3.
// R15/R8: native-exp screen correct (s<2 identity, ~3.4% pass) but plumbing ate
//      the win: per-voxel ballot->LDS-atomic->ds_bpermute chain (~250cy x8) and
//      global re-gather (+26MB FETCH). dur 44us, VALU 11us.
// R16 (this round): keep the screen, fix the plumbing:
//      - wave-local queue: pos = wq + mbcnt(ballot), wq(SGPR) += popc -- no LDS
//        atomic, no bpermute in the chain;
//      - survivors' 4 logits stashed to LDS (float4, per-wave segment) at screen
//        time -> slow phase reads LDS, NO global re-gather;
//      - slow phase per-wave (<=2 rounds of 64), results in registers, emitted
//        in phase 3 from registers;
//      - overflow (adversarial only): inline precise fallback into pk[8] regs --
//        correctness never depends on queue capacity.

// ---------------- Kernel 1: streaming pass ----------------
__global__ __launch_bounds__(BT) void fused_stream(const float* __restrict__ logits,
                                                   unsigned int* __restrict__ cnt,
                                                   unsigned int* __restrict__ gh,
                                                   uint2* __restrict__ cand,
                                                   int cap) {
    __shared__ unsigned int lh[Cn * NBINS];   // 16.4 KB per-class local radix hist
    __shared__ float4 qlog[8][QW];            // 16 KB  per-wave survivor logits
    __shared__ unsigned short qidx[8][QW];    // 2 KB   per-wave survivor local voxel ids
    __shared__ unsigned int lcut[Cn], cls_cnt[Cn], cls_base[Cn], cls_pos[Cn];
    const int b = blockIdx.y;
    const int t = threadIdx.x;
    const int lane = t & 63;
    const int wv = t >> 6;
    for (int j = t; j < Cn * NBINS; j += BT) lh[j] = 0u;
    if (t < Cn) { lcut[t] = 0u; cls_cnt[t] = 0u; cls_pos[t] = 0u; }
    __syncthreads();

    const float* base = logits + (size_t)b * Cn * Sn;
    const f32x4* s0 = (const f32x4*)base;
    const f32x4* s1 = (const f32x4*)(base + Sn);
    const f32x4* s2 = (const f32x4*)(base + 2 * Sn);
    const f32x4* s3 = (const f32x4*)(base + 3 * Sn);
    const int qs = blockIdx.x * (PB / 4);

    // phase 1: native-exp screen over all voxels. Identity: m=max(l) => e_max=1
    // => p>0.5 <=> s_ocml<2. |s~-s_ocml| <= ~2^-18; margin 2^-10 is conservative
    // 400x over. Screen-passers (~3.4%) go to the per-wave LDS queue with their
    // logits; overflow (impossible for real data) falls back to inline precise.
    unsigned int pk[PB / BT] = {0u, 0u, 0u, 0u, 0u, 0u, 0u, 0u};  // fallback slots
    unsigned int wq = 0u;   // this wave's queue count (uniform -> SGPR)
    #pragma unroll
    for (int it = 0; it < PB / 4 / BT; ++it) {   // 2 iterations
        int q = qs + it * BT + t;
        f32x4 v0 = s0[q], v1 = s1[q], v2 = s2[q], v3 = s3[q];
        #pragma unroll
        for (int k = 0; k < 4; ++k) {
            float l0 = v0[k], l1 = v1[k], l2 = v2[k], l3 = v3[k];
            float m = fmaxf(fmaxf(l0, l1), fmaxf(l2, l3));
            float st = ((__expf(l0 - m) + __expf(l1 - m)) + __expf(l2 - m))
                       + __expf(l3 - m);
            bool c = st < 2.0009766f;   // 2 + 2^-10
            unsigned long long mk = __ballot(c);
            unsigned int nb = __builtin_amdgcn_mbcnt_lo((unsigned int)mk, 0u);
            nb = __builtin_amdgcn_mbcnt_hi((unsigned int)(mk >> 32), nb);
            unsigned int pos = wq + nb;          // per-lane slot in wave segment
            if (c) {
                if (pos < QW) {
                    qlog[wv][pos] = make_float4(l0, l1, l2, l3);
                    qidx[wv][pos] = (unsigned short)((it * BT + t) * 4 + k);
                } else {
                    // overflow fallback: precise inline (adversarial data only)
                    int cm; float p;
                    softmax_argmax4(l0, l1, l2, l3, &cm, &p);
                    if (p > THRf) {
                        unsigned int off = __float_as_uint(p) - 0x3F000000u;
                        atomicAdd(&lh[cm * NBINS + (int)(off >> 13)], 1u);
                        pk[it * 4 + k] = (off << 2) | (unsigned int)cm;
                    }
                }
            }
            wq += (unsigned int)__popcll(mk);    // uniform update
        }
    }

    // phase 1-slow: per-wave precise pass over its own queue (<=2 rounds of 64).
    // Same-wave LDS producer/consumer -> no barrier needed; results stay in regs.
    const unsigned int nq = min(wq, (unsigned int)QW);
    unsigned int spv0 = 0u, sidx0 = 0u, spv1 = 0u, sidx1 = 0u;
    if ((unsigned int)lane < nq) {
        float4 L = qlog[wv][lane];
        int cm; float p;
        softmax_argmax4(L.x, L.y, L.z, L.w, &cm, &p);
        if (p > THRf) {
            unsigned int off = __float_as_uint(p) - 0x3F000000u;   // 1..0x800000
            atomicAdd(&lh[cm * NBINS + (int)(off >> 13)], 1u);     // no-return ds_add
            spv0 = (off << 2) | (unsigned int)cm;                  // 26 bits, nonzero
            sidx0 = qidx[wv][lane];
        }
    }
    if ((unsigned int)(64 + lane) < nq) {
        float4 L = qlog[wv][64 + lane];
        int cm; float p;
        softmax_argmax4(L.x, L.y, L.z, L.w, &cm, &p);
        if (p > THRf) {
            unsigned int off = __float_as_uint(p) - 0x3F000000u;
            atomicAdd(&lh[cm * NBINS + (int)(off >> 13)], 1u);
            spv1 = (off << 2) | (unsigned int)cm;
            sidx1 = qidx[wv][64 + lane];
        }
    }
    __syncthreads();

    // phase 2: wave w (w<4) computes local cutoff for class w (64 lanes x 17 bins).
    // Entries below the local cutoff have >=32 strictly-greater local entries ->
    // global rank >= 32 -> safe to drop. Union over blocks is a superset of top-32.
    // The break-time acc = count of entries in bins >= lcut = exact emit count.
    {
        if (wv < Cn) {
            const unsigned int* h = &lh[wv * NBINS];
            const int lo = lane * 17;
            unsigned int cs = 0;
            #pragma unroll
            for (int k = 0; k < 17; ++k) {
                int bin = lo + k;
                if (bin < NBINS) cs += h[bin];
            }
            unsigned int S = cs;  // inclusive suffix sum over lanes [lane..63]
            #pragma unroll
            for (int off = 1; off < 64; off <<= 1) {
                unsigned int v = __shfl_down(S, off, 64);
                if (lane + off < 64) S += v;
            }
            unsigned int suf = S - cs;
            if (S >= NPTS && suf < NPTS) {   // exactly one lane (when total >= 32)
                unsigned int acc = suf;
                int hi = min(lo + 16, NBINS - 1);
                for (int bin = hi; bin >= lo; --bin) {
                    acc += h[bin];
                    if (acc >= NPTS) {
                        lcut[wv] = (unsigned int)bin;
                        cls_cnt[wv] = acc;
                        break;
                    }
                }
            }
            if (lane == 0 && S < NPTS) cls_cnt[wv] = S;  // total<32: lcut=0, emit all
        }
    }
    __syncthreads();

    // phase 2.5: publish surviving bins (bin >= lcut, nonzero) into the global
    // per-(b,c) histogram == exactly the histogram of all emitted candidates.
    // Plain atomicAdd (device-scope by default); ~35 per class per block.
    {
        if (wv < Cn) {
            const unsigned int* h = &lh[wv * NBINS];
            unsigned int* g = gh + (size_t)(b * Cn + wv) * NBINS;
            for (int bin = (int)lcut[wv] + lane; bin < NBINS; bin += 64) {
                unsigned int v = h[bin];
                if (v) atomicAdd(&g[bin], v);
            }
        }
    }
    // reservation: one global atomic per (block, class)
    if (t < Cn && cls_cnt[t] > 0)
        cls_base[t] = atomicAdd(&cnt[b * Cn + t], cls_cnt[t]);
    __syncthreads();

    // phase 3: emit survivors (~144/block) from slow-phase registers + fallback
    // regs. Plain stores: kernel boundary makes them visible to select_emit.
    {
        if (spv0 != 0u) {
            unsigned int cm = spv0 & 3u;
            if ((spv0 >> 15) >= lcut[cm]) {
                unsigned int pos = cls_base[cm] + atomicAdd(&cls_pos[cm], 1u);
                if (pos < (unsigned int)cap)
                    cand[(size_t)(b * Cn + cm) * cap + pos] =
                        make_uint2(0x3F000000u + (spv0 >> 2),
                                   (unsigned int)(qs * 4) + sidx0);
            }
        }
        if (spv1 != 0u) {
            unsigned int cm = spv1 & 3u;
            if ((spv1 >> 15) >= lcut[cm]) {
                unsigned int pos = cls_base[cm] + atomicAdd(&cls_pos[cm], 1u);
                if (pos < (unsigned int)cap)
                    cand[(size_t)(b * Cn + cm) * cap + pos] =
                        make_uint2(0x3F000000u + (spv1 >> 2),
                                   (unsigned int)(qs * 4) + sidx1);
            }
        }
        #pragma unroll
        for (int j = 0; j < PB / BT; ++j) {   // fallback slots (normally all 0)
            unsigned int pv = pk[j];
            if (pv != 0u) {
                unsigned int cm = pv & 3u;
                if ((pv >> 15) >= lcut[cm]) {
                    unsigned int pos = cls_base[cm] + atomicAdd(&cls_pos[cm], 1u);
                    if (pos < (unsigned int)cap) {
                        unsigned int idx =
                            (unsigned int)((qs + (j >> 2) * BT + t) * 4 + (j & 3));
                        cand[(size_t)(b * Cn + cm) * cap + pos] =
                            make_uint2(0x3F000000u + (pv >> 2), idx);
                    }
                }
            }
        }
    }
}

// ---------------- Kernel 2: per-(b,c) exact selection + emit ----------------
// One block per (b,c). gh is already the complete candidate histogram, so this
// kernel does: exact cutoff scan -> ONE branch-free MLP filter pass over cand ->
// O(m^2) exact rank (m ~ 80) -> cross-class compaction by the last finisher of
// each batch (R0-proven 8-block threadfence pattern).
__global__ __launch_bounds__(BT2) void select_emit(const unsigned int* __restrict__ cnt,
                                                   const unsigned int* __restrict__ gh,
                                                   const uint2* __restrict__ cand,
                                                   int cap,
                                                   unsigned int* __restrict__ done,
                                                   unsigned int* __restrict__ validn,
                                                   uint2* __restrict__ topk,
                                                   int* __restrict__ out) {
    __shared__ unsigned int lh[NBINS];        // 4.1 KB this class's global hist
    __shared__ uint2 fbuf[FB];                // 8.2 KB survivors
    __shared__ unsigned int s_T, s_m, s_old;
    __shared__ int pre[Cn + 1];
    const int bc = blockIdx.x, t = threadIdx.x;
    const int b = bc >> 2;
    const int lane = t & 63;

    for (int j = t; j < NBINS; j += BT2) lh[j] = gh[(size_t)bc * NBINS + j];
    if (t == 0) { s_T = 0u; s_m = 0u; }
    __syncthreads();
    const int n = min((int)cnt[bc], cap);

    // exact global cutoff: wave 0 scans the 1025 bins
    if (t < 64) {
        const int lo = lane * 17;
        unsigned int cs = 0;
        #pragma unroll
        for (int k = 0; k < 17; ++k) {
            int bin = lo + k;
            if (bin < NBINS) cs += lh[bin];
        }
        unsigned int S = cs;
        #pragma unroll
        for (int off = 1; off < 64; off <<= 1) {
            unsigned int v = __shfl_down(S, off, 64);
            if (lane + off < 64) S += v;
        }
        unsigned int suf = S - cs;
        if (S >= NPTS && suf < NPTS) {
            unsigned int acc = suf;
            int hi = min(lo + 16, NBINS - 1);
            for (int bin = hi; bin >= lo; --bin) {
                acc += lh[bin];
                if (acc >= NPTS) { s_T = (unsigned int)bin; break; }
            }
        }
        // S < NPTS: s_T stays 0 -> keep everything
    }
    __syncthreads();
    const unsigned int T = s_T;

    // single filtered pass, branch-free 8-deep load batches (true MLP)
    {
        const uint2* src = cand + (size_t)bc * cap;
        for (int j0 = t; j0 < n; j0 += BT2 * 8) {
            uint2 e[8];
            #pragma unroll
            for (int k = 0; k < 8; ++k) {
                int j = j0 + k * BT2;
                e[k] = src[j < n ? j : (n > 0 ? n - 1 : 0)];   // clamped: always issues
            }
            #pragma unroll
            for (int k = 0; k < 8; ++k) {
                int j = j0 + k * BT2;
                if (j < n && (unsigned int)bin_of_bits(e[k].x) >= T) {
                    unsigned int pos = atomicAdd(&s_m, 1u);
                    if (pos < FB) fbuf[pos] = e[k];
                }
            }
        }
    }
    __syncthreads();

    // exact rank with jax tie-break (higher prob first; equal prob -> lower idx
    // first); ranks distinct (idx unique per class). ~80 survivors.
    const int m = min((int)s_m, FB);
    const int vn = min(n, NPTS);
    if (t == 0) validn[bc] = (unsigned int)vn;
    for (int i = t; i < m; i += BT2) {
        uint2 e = fbuf[i];
        int rank = 0;
        for (int j = 0; j < m; ++j) {
            uint2 o = fbuf[j];
            rank += (int)((o.x > e.x) || (o.x == e.x && o.y < e.y));
        }
        if (rank < vn) topk[bc * NPTS + rank] = e;
    }

    // epilogue: last finishing block of this batch emits (8 blocks total pay the
    // fence -- the R0-proven pattern).
    __threadfence();
    __syncthreads();
    if (t == 0) s_old = atomicAdd(&done[b], 1u);
    __syncthreads();
    if (s_old != 3u) return;
    __threadfence();   // acquire: see the other 3 classes' topk/validn

    if (t == 0) {
        int acc = 0;
        for (int oc = 0; oc < Cn; ++oc) {
            pre[oc] = acc;
            acc += (int)validn[b * Cn + ((oc + 1) & 3)];   // class order [1,2,3,0]
        }
        pre[Cn] = acc;
    }
    __syncthreads();

    if (t < Cn * NPTS) {   // 128 output slots for batch b
        const int j = t;
        int label = -1, z = 0, y = 0, x = 0;
        if (j < pre[Cn]) {
            int oc = 0;
            while (j >= pre[oc + 1]) ++oc;
            int c = (oc + 1) & 3;
            int r = j - pre[oc];
            uint2 e = topk[(b * Cn + c) * NPTS + r];
            int idx = (int)e.y;
            z = idx >> 14;          // idx / (128*128)
            y = (idx >> 7) & 127;   // (idx / 128) % 128
            x = idx & 127;          // idx % 128
            label = c;
        }
        int* coords = out;                       // 2*128*3 = 768 ints
        int* labels = out + Bn * Cn * NPTS * 3;  // then 2*128 = 256 ints
        int bo = b * Cn * NPTS + j;
        coords[bo * 3 + 0] = z;
        coords[bo * 3 + 1] = y;
        coords[bo * 3 + 2] = x;
        labels[bo] = label;
    }
}

extern "C" void kernel_launch(void* const* d_in, const int* in_sizes, int n_in,
                              void* d_out, int out_size, void* d_ws, size_t ws_size,
                              hipStream_t stream) {
    const float* logits = (const float*)d_in[0];
    int* out = (int*)d_out;

    // Workspace layout (zeroed region first, contiguous: cnt, done, gh)
    unsigned int* cnt = (unsigned int*)d_ws;             // 8 u32    @0
    unsigned int* done = cnt + Bn * Cn;                  // 2 u32    @32
    unsigned int* gh = done + Bn;                        // 8*1025   @40
    unsigned int* validn = gh + Bn * Cn * NBINS;         // 8 u32    @32840
    uint2* topk = (uint2*)(validn + Bn * Cn);            // 256 uint2 @32872 (8-aligned)
    uint2* cand = topk + Bn * Cn * NPTS;                 // @34920
    size_t fixed = (size_t)((char*)cand - (char*)d_ws);
    int cap = (int)((ws_size - fixed) / (Bn * Cn * sizeof(uint2)));
    if (cap > (1 << 18)) cap = 1 << 18;   // 256k entries/bc >> the ~18k expected
    if (cap < 4096) cap = 4096;

    // Zero cnt + done + gh (contiguous, ~33 KB; workspace is harness-poisoned)
    hipMemsetAsync(cnt, 0, (size_t)(Bn * Cn + Bn + Bn * Cn * NBINS) * sizeof(unsigned int),
                   stream);

    dim3 grid(Sn / PB, Bn);   // (512, 2) = 1024 blocks, co-resident at 4 blk/CU
    fused_stream<<<grid, BT, 0, stream>>>(logits, cnt, gh, cand, cap);
    select_emit<<<Bn * Cn, BT2, 0, stream>>>(cnt, gh, cand, cap, done, validn, topk, out);
}